// Round 1
// 1364.095 us; speedup vs baseline: 1.4558x; 1.4558x over previous
//
#include <hip/hip_runtime.h>
#include <hip/hip_bf16.h>

#define N0 200000
#define N1 150000
#define N2 120000
#define N3 100000
#define E0 2000000
#define E1 1000000
#define E2 500000
#define ESUB 250000

// cnt/offs/cur super-array layout: [c2 | c0s | c0d | c1]
// c2 FIRST so the g2 pool segment is exactly pool[0..E2) -> x3b can alias pool+E2.
#define IC2 0
#define IC0S N3
#define IC0D (N3 + N1)
#define IC1 (N3 + 2 * N1)
#define LTOT (N3 + 2 * N1 + N2)      // 520000
#define NBLK ((LTOT + 2047) / 2048)  // 254 (fits one 256-thread scan block)
#define POOLCAP (E2 + 2 * E0 + E1)   // 5,500,000 slots (upper bound)

typedef float f32x4 __attribute__((ext_vector_type(4)));
typedef __bf16 bf16x8 __attribute__((ext_vector_type(8)));

// ---------------- counting ----------------
__global__ void k_cnt0(const int* __restrict__ src, const int* __restrict__ dst,
                       int* __restrict__ cnt) {
    int i = blockIdx.x * blockDim.x + threadIdx.x;
    if (i >= E0) return;
    int s = src[i];
    if (s < N1) atomicAdd(&cnt[IC0S + s], 1);
    atomicAdd(&cnt[IC0D + dst[i]], 1);
}

__global__ void k_cnt2(const int* __restrict__ src, const int* __restrict__ dst, int n,
                       int* __restrict__ dego, int* __restrict__ cnt, int cbase) {
    int i = blockIdx.x * blockDim.x + threadIdx.x;
    if (i >= n) return;
    atomicAdd(&dego[src[i]], 1);
    atomicAdd(&cnt[cbase + dst[i]], 1);
}

// ---------------- exclusive scan (3-kernel hierarchical, exact) ----------------
__global__ __launch_bounds__(256) void k_scan1(const int* __restrict__ cnt,
                                               int* __restrict__ offs, int* __restrict__ bsum) {
    __shared__ int ts[256];
    int t = threadIdx.x;
    int base = blockIdx.x * 2048 + t * 8;
    int loc[8];
    int s = 0;
#pragma unroll
    for (int j = 0; j < 8; j++) {
        int v = (base + j < LTOT) ? cnt[base + j] : 0;
        loc[j] = s; s += v;
    }
    ts[t] = s;
    __syncthreads();
    for (int off = 1; off < 256; off <<= 1) {
        int x = (t >= off) ? ts[t - off] : 0;
        __syncthreads();
        ts[t] += x;
        __syncthreads();
    }
    int excl = ts[t] - s;
#pragma unroll
    for (int j = 0; j < 8; j++)
        if (base + j < LTOT) offs[base + j] = excl + loc[j];
    if (t == 255) bsum[blockIdx.x] = ts[255];
}

__global__ __launch_bounds__(256) void k_scan2(const int* __restrict__ bsum,
                                               int* __restrict__ bscan) {
    __shared__ int ts[256];
    int t = threadIdx.x;
    int v = (t < NBLK) ? bsum[t] : 0;
    ts[t] = v;
    __syncthreads();
    for (int off = 1; off < 256; off <<= 1) {
        int x = (t >= off) ? ts[t - off] : 0;
        __syncthreads();
        ts[t] += x;
        __syncthreads();
    }
    if (t < NBLK) bscan[t] = ts[t] - v;
}

__global__ void k_scan3(int* __restrict__ offs, const int* __restrict__ bscan) {
    int i = blockIdx.x * 256 + threadIdx.x;
    if (i < LTOT) offs[i] += bscan[i >> 11];
}

// ---------------- binning: store payload VALUE in pool (typ for g0, src for g1/g2) ----------------
__global__ void k_bin0(const int* __restrict__ typ, const int* __restrict__ src,
                       const int* __restrict__ dst, const int* __restrict__ offs,
                       int* __restrict__ cur, int* __restrict__ pool) {
    int i = blockIdx.x * blockDim.x + threadIdx.x;
    if (i >= E0) return;
    int ty = typ[i];
    int s = src[i];
    if (s < N1) {
        int p = atomicAdd(&cur[IC0S + s], 1);
        pool[offs[IC0S + s] + p] = ty;
    }
    int d = dst[i];
    int p2 = atomicAdd(&cur[IC0D + d], 1);
    pool[offs[IC0D + d] + p2] = ty;
}

__global__ void k_bin(const int* __restrict__ src, const int* __restrict__ dst, int n,
                      const int* __restrict__ offs, int* __restrict__ cur,
                      int* __restrict__ pool, int cbase) {
    int i = blockIdx.x * blockDim.x + threadIdx.x;
    if (i >= n) return;
    int d = dst[i];
    int p = atomicAdd(&cur[cbase + d], 1);
    pool[offs[cbase + d] + p] = src[i];
}

// ---------------- layer 0: gather rel_emb means + 32x32 matvecs -> h1 (fused) ----------------
__global__ __launch_bounds__(256) void k_layer0(const int* __restrict__ cnt, const int* __restrict__ offs,
                                                const int* __restrict__ pool, const float* __restrict__ rel_emb,
                                                const float* __restrict__ W_out, const float* __restrict__ b_out,
                                                const float* __restrict__ W_in, const float* __restrict__ b_in,
                                                const int* __restrict__ deg1o, float* __restrict__ h1) {
    __shared__ float S[4][64];
    int t = threadIdx.x;
    int nl = t >> 6;        // node within block
    int lane = t & 63;
    int half = lane >> 5;   // 0 = out(src-agg), 1 = in(dst-agg)
    int k = lane & 31;
    int n = blockIdx.x * 4 + nl;
    if (n >= N1) return;
    int ci = (half ? IC0D : IC0S) + n;
    int dg = cnt[ci];
    int off = offs[ci];
    float acc = 0.0f;
    for (int cb = 0; cb < dg; cb += 32) {
        int rem = dg - cb; if (rem > 32) rem = 32;
        int ty_all = (k < rem) ? pool[off + cb + k] : 0;
        for (int i = 0; i < rem; i++) {
            int ty = __shfl(ty_all, i, 32);     // broadcast within the 32-lane half
            acc += rel_emb[ty * 32 + k];
        }
    }
    S[nl][lane] = (dg > 0) ? acc / (float)dg : 0.0f;  // mean vector component
    __syncthreads();
    // output col j = lane: j<32 -> S_out @ W_out col j ; j>=32 -> S_in @ W_in col j-32
    const float* W = half ? W_in : W_out;
    float b = half ? b_in[k] : b_out[k];
    float r = 0.0f;
    if (dg > 0) {
        float d = 0.0f;
#pragma unroll
        for (int kk = 0; kk < 32; kk++) d += S[nl][half * 32 + kk] * W[kk * 32 + k];
        r = d + b;   // deg==0 -> 0 (mean_agg yields zero row, no bias)
    }
    h1[(size_t)n * 64 + lane] = r * rsqrtf(fmaxf((float)deg1o[n], 1.0f));
}

// ---------------- conv1 with fused gather: h2 = relu((gather(h1)*rsqrt(deg1_i)) @ W1 + b1) * rsqrt(deg2_o) ----------------
__global__ __launch_bounds__(256) void k_conv1g(const float* __restrict__ h1,
                                                const int* __restrict__ cnt, const int* __restrict__ offs,
                                                const int* __restrict__ pool, const int* __restrict__ deg2o,
                                                const float* __restrict__ W1, const float* __restrict__ b1,
                                                float* __restrict__ h2) {
    __shared__ float row[8][64];
    int base = blockIdx.x * 8;
    int t = threadIdx.x;
    int wave = t >> 6, lane = t & 63;
#pragma unroll
    for (int rr = 0; rr < 2; rr++) {
        int m = wave * 2 + rr;
        int rg = base + m;                       // grid exact: rg < N2
        int dg = cnt[IC1 + rg];
        int off = offs[IC1 + rg];
        float acc = 0.0f;
        for (int cb = 0; cb < dg; cb += 64) {
            int rem = dg - cb; if (rem > 64) rem = 64;
            int s_all = (lane < rem) ? pool[off + cb + lane] : 0;
            for (int i = 0; i < rem; i++) {
                int s = __shfl(s_all, i, 64);
                acc += h1[(size_t)s * 64 + lane];
            }
        }
        row[m][lane] = acc * rsqrtf(fmaxf((float)dg, 1.0f));
    }
    __syncthreads();
    float acc8[8] = {0, 0, 0, 0, 0, 0, 0, 0};
    for (int k = 0; k < 64; k++) {
        float w = W1[k * 256 + t];
#pragma unroll
        for (int m = 0; m < 8; m++) acc8[m] += row[m][k] * w;
    }
    float bb = b1[t];
#pragma unroll
    for (int m = 0; m < 8; m++) {
        float v = fmaxf(acc8[m] + bb, 0.0f) * rsqrtf(fmaxf((float)deg2o[base + m], 1.0f));
        h2[(size_t)(base + m) * 256 + t] = v;
    }
}

// ---------------- pack W (K x 256 f32, row-major) into MFMA B-fragment order (bf16) ----------------
__global__ void k_pack(const float* __restrict__ W, __bf16* __restrict__ Wp, int ksteps) {
    int idx = blockIdx.x * 256 + threadIdx.x;
    int j = idx & 7;
    int lane = (idx >> 3) & 63;
    int rest = idx >> 9;
    int ks = rest % ksteps;
    int tn = rest / ksteps;
    int k = ks * 32 + ((lane >> 4) * 8) + j;
    int n = tn * 16 + (lane & 15);
    Wp[idx] = (__bf16)W[k * 256 + n];
}

// ---------------- conv2 MFMA with fused gather: x3b = bf16(relu((gather(h2)*rsqrt(deg2_i)) @ W2 + b2)) ----------------
__global__ __launch_bounds__(256) void k_conv2g(const float* __restrict__ h2,
                                                const int* __restrict__ cnt, const int* __restrict__ offs,
                                                const int* __restrict__ pool,
                                                const __bf16* __restrict__ W2p,
                                                const float* __restrict__ b2v,
                                                __bf16* __restrict__ x3b) {
    __shared__ __bf16 At[64][264];   // +8 pad -> 2-way LDS conflicts only
    int t = threadIdx.x;
    int base = blockIdx.x * 64;
    int wave = t >> 6, lane = t & 63;
    // gather phase: each wave owns 16 rows; each lane owns 4 contiguous cols (float4)
#pragma unroll 1
    for (int rr = 0; rr < 16; rr++) {
        int row = wave * 16 + rr;
        int rg = base + row;
        f32x4 acc = {0.0f, 0.0f, 0.0f, 0.0f};
        int dg = 0;
        if (rg < N3) {
            dg = cnt[IC2 + rg];
            int off = offs[IC2 + rg];
            for (int cb = 0; cb < dg; cb += 64) {
                int rem = dg - cb; if (rem > 64) rem = 64;
                int s_all = (lane < rem) ? pool[off + cb + lane] : 0;
                for (int i = 0; i < rem; i++) {
                    int s = __shfl(s_all, i, 64);
                    const f32x4 v = *(const f32x4*)(h2 + (size_t)s * 256 + lane * 4);
                    acc += v;
                }
            }
        }
        float sc = rsqrtf(fmaxf((float)dg, 1.0f));
        union { __bf16 b[4]; uint2 u; } cv;
        cv.b[0] = (__bf16)(acc[0] * sc); cv.b[1] = (__bf16)(acc[1] * sc);
        cv.b[2] = (__bf16)(acc[2] * sc); cv.b[3] = (__bf16)(acc[3] * sc);
        *(uint2*)&At[row][lane * 4] = cv.u;
    }
    __syncthreads();
    int q = lane >> 4, r16 = lane & 15;
    f32x4 acc[4][4] = {};
    for (int ks = 0; ks < 8; ks++) {
        bf16x8 a[4], b[4];
        int ko = ks * 32 + q * 8;
#pragma unroll
        for (int mt = 0; mt < 4; mt++)
            a[mt] = *(const bf16x8*)&At[mt * 16 + r16][ko];
#pragma unroll
        for (int i = 0; i < 4; i++) {
            int tn = wave * 4 + i;
            b[i] = *(const bf16x8*)&W2p[((size_t)(tn * 8 + ks) * 64 + lane) * 8];
        }
#pragma unroll
        for (int mt = 0; mt < 4; mt++)
#pragma unroll
            for (int i = 0; i < 4; i++)
                acc[mt][i] = __builtin_amdgcn_mfma_f32_16x16x32_bf16(a[mt], b[i], acc[mt][i], 0, 0, 0);
    }
#pragma unroll
    for (int mt = 0; mt < 4; mt++) {
#pragma unroll
        for (int i = 0; i < 4; i++) {
            int col = (wave * 4 + i) * 16 + r16;
            float bb = b2v[col];
#pragma unroll
            for (int rr = 0; rr < 4; rr++) {
                int row = base + mt * 16 + q * 4 + rr;
                if (row < N3)
                    x3b[(size_t)row * 256 + col] = (__bf16)fmaxf(acc[mt][i][rr] + bb, 0.0f);
            }
        }
    }
}

// ---------------- final via MFMA: out = [x3b[ss], x3b[sd]] @ Wfc + bfc ----------------
__global__ __launch_bounds__(256) void k_final_mfma(const int* __restrict__ ss, const int* __restrict__ sd,
                                                    const __bf16* __restrict__ x3b,
                                                    const __bf16* __restrict__ Wp,
                                                    const float* __restrict__ bfc,
                                                    float* __restrict__ out) {
    __shared__ __bf16 At[64][520];   // +8 pad -> 2-way LDS conflicts only
    __shared__ int eidx[128];
    int t = threadIdx.x;
    int base = blockIdx.x * 64;
    if (t < 64)       { int e = base + t;      eidx[t] = ss[e < ESUB ? e : ESUB - 1]; }
    else if (t < 128) { int e = base + t - 64; eidx[t] = sd[e < ESUB ? e : ESUB - 1]; }
    __syncthreads();
#pragma unroll
    for (int it = 0; it < 16; it++) {
        int c = it * 256 + t;       // 0..4095
        int row = c >> 6;           // 0..63
        int cpos = c & 63;          // 16B chunk within 512-elem row
        int half = cpos >> 5;
        int off8 = (cpos & 31) * 8;
        int node = eidx[half * 64 + row];
        uint4 v = *(const uint4*)(x3b + (size_t)node * 256 + off8);
        *(uint4*)&At[row][half * 256 + off8] = v;
    }
    __syncthreads();
    int wave = t >> 6, lane = t & 63;
    int q = lane >> 4, r16 = lane & 15;
    f32x4 acc[4][4] = {};
    for (int ks = 0; ks < 16; ks++) {
        bf16x8 a[4], b[4];
        int ko = ks * 32 + q * 8;
#pragma unroll
        for (int mt = 0; mt < 4; mt++)
            a[mt] = *(const bf16x8*)&At[mt * 16 + r16][ko];
#pragma unroll
        for (int i = 0; i < 4; i++) {
            int tn = wave * 4 + i;
            b[i] = *(const bf16x8*)&Wp[((size_t)(tn * 16 + ks) * 64 + lane) * 8];
        }
#pragma unroll
        for (int mt = 0; mt < 4; mt++)
#pragma unroll
            for (int i = 0; i < 4; i++)
                acc[mt][i] = __builtin_amdgcn_mfma_f32_16x16x32_bf16(a[mt], b[i], acc[mt][i], 0, 0, 0);
    }
#pragma unroll
    for (int mt = 0; mt < 4; mt++) {
#pragma unroll
        for (int i = 0; i < 4; i++) {
            int col = (wave * 4 + i) * 16 + r16;
            float bb = bfc[col];
#pragma unroll
            for (int rr = 0; rr < 4; rr++) {
                int row = base + mt * 16 + q * 4 + rr;
                if (row < ESUB)
                    out[(size_t)row * 256 + col] = acc[mt][i][rr] + bb;
            }
        }
    }
}

extern "C" void kernel_launch(void* const* d_in, const int* in_sizes, int n_in,
                              void* d_out, int out_size, void* d_ws, size_t ws_size,
                              hipStream_t stream) {
    const int* e0_type = (const int*)d_in[0];
    const int* e0_src  = (const int*)d_in[1];
    const int* e0_dst  = (const int*)d_in[2];
    const int* e1_src  = (const int*)d_in[3];
    const int* e1_dst  = (const int*)d_in[4];
    const int* e2_src  = (const int*)d_in[5];
    const int* e2_dst  = (const int*)d_in[6];
    const int* sub_src = (const int*)d_in[7];
    const int* sub_dst = (const int*)d_in[8];
    const float* rel_emb = (const float*)d_in[9];
    const float* W_out   = (const float*)d_in[10];
    const float* b_out   = (const float*)d_in[11];
    const float* W_in    = (const float*)d_in[12];
    const float* b_in    = (const float*)d_in[13];
    const float* W1      = (const float*)d_in[14];
    const float* b1      = (const float*)d_in[15];
    const float* W2      = (const float*)d_in[16];
    const float* b2v     = (const float*)d_in[17];
    const float* Wfc     = (const float*)d_in[18];
    const float* bfc     = (const float*)d_in[19];
    float* out = (float*)d_out;

    // ---- workspace layout (4-byte units), total ~191 MB ----
    // [cnt | cur | deg1o | deg2o | offs | bsum | bscan | pool | h1 | h2 | Wfcp | W2p]
    int* cnt   = (int*)d_ws;
    int* cur   = cnt + LTOT;
    int* deg1o = cur + LTOT;           // e1_src out-degree over N1
    int* deg2o = deg1o + N1;           // e2_src out-degree over N2
    int* offs  = deg2o + N2;
    int* bsum  = offs + LTOT;
    int* bscan = bsum + 512;
    int* pool  = bscan + 512;          // POOLCAP slots; g2 = pool[0..E2)
    float* h1  = (float*)(pool + POOLCAP);           // N1*64
    float* h2  = h1 + (size_t)N1 * 64;               // N2*256
    __bf16* Wfcp = (__bf16*)(h2 + (size_t)N2 * 256); // 512*256 bf16
    __bf16* W2p  = Wfcp + 131072;                    // 256*256 bf16
    // x3b aliases the dead g0s/g0d/g1 pool segments + h1 (live only [conv2g, final))
    __bf16* x3b  = (__bf16*)(pool + E2);

    const int BT = 256;

    // zero cnt + cur + deg1o + deg2o (contiguous, 5.24 MB)
    hipMemsetAsync(d_ws, 0, (size_t)(2 * LTOT + N1 + N2) * sizeof(int), stream);

    // pack weights (independent of zeroed region)
    k_pack<<<512, BT, 0, stream>>>(Wfc, Wfcp, 16);
    k_pack<<<256, BT, 0, stream>>>(W2, W2p, 8);

    // count
    k_cnt0<<<(E0 + BT - 1) / BT, BT, 0, stream>>>(e0_src, e0_dst, cnt);
    k_cnt2<<<(E1 + BT - 1) / BT, BT, 0, stream>>>(e1_src, e1_dst, E1, deg1o, cnt, IC1);
    k_cnt2<<<(E2 + BT - 1) / BT, BT, 0, stream>>>(e2_src, e2_dst, E2, deg2o, cnt, IC2);

    // exclusive scan of cnt -> offs
    k_scan1<<<NBLK, BT, 0, stream>>>(cnt, offs, bsum);
    k_scan2<<<1, BT, 0, stream>>>(bsum, bscan);
    k_scan3<<<(LTOT + BT - 1) / BT, BT, 0, stream>>>(offs, bscan);

    // bin (payload values into pool)
    k_bin0<<<(E0 + BT - 1) / BT, BT, 0, stream>>>(e0_type, e0_src, e0_dst, offs, cur, pool);
    k_bin<<<(E1 + BT - 1) / BT, BT, 0, stream>>>(e1_src, e1_dst, E1, offs, cur, pool, IC1);
    k_bin<<<(E2 + BT - 1) / BT, BT, 0, stream>>>(e2_src, e2_dst, E2, offs, cur, pool, IC2);

    // layer 0: gather + combine -> h1
    k_layer0<<<(N1 + 3) / 4, BT, 0, stream>>>(cnt, offs, pool, rel_emb, W_out, b_out, W_in, b_in, deg1o, h1);

    // conv1 (fused gather) -> h2
    k_conv1g<<<N2 / 8, BT, 0, stream>>>(h1, cnt, offs, pool, deg2o, W1, b1, h2);

    // conv2 (fused gather, MFMA) -> x3b
    k_conv2g<<<(N3 + 63) / 64, BT, 0, stream>>>(h2, cnt, offs, pool, W2p, b2v, x3b);

    // final edge MLP (MFMA)
    k_final_mfma<<<(ESUB + 63) / 64, BT, 0, stream>>>(sub_src, sub_dst, x3b, Wfcp, bfc, out);
}